// Round 14
// baseline (6421.674 us; speedup 1.0000x reference)
//
#include <hip/hip_runtime.h>
#include <math.h>
#include <float.h>
#include <mutex>

// Problem constants (match reference)
#define N_PTS  32768
#define NS     2048      // N_PTS/16 downsample
#define CD     256
#define KC     5
#define TPB    512       // kmeans kernel threads/block
#define TPB_F  1024      // FPS kernel threads/block (round-14: halve sync agents)
#define NB_F   4         // FPS blocks per branch: 8192 pts/block, 8 pts/thread
#define NB_K   8         // kmeans blocks per branch (distributed kmeans)
#define LPTS   256       // NS/NB_K local sampled points per kmeans block
#define APAY_N 1285      // A-payload floats: counts[5] + sums[5*256]
#define MAX_IT 100
#define TOLV   1e-3f
#define DYN_K  131072    // kmeans dyn LDS: pos_s(24576) + stag/wbuf + mdbuf(@98304)

struct Sm {
  int   sel[NS];        // FPS-selected indices into the 32768 points (full copy)
  int   idx[NS];        // cluster assignment (position phase: 2048; feature phase: local 256)
  float cm[KC][CD];     // feature-space centroids (globally reduced, identical per block)
  float cc2h[KC];       // 0.5*|c|^2
  float c3[KC][3];      // position-space centroids
  float cnt[KC];        // counts (position phase: global; feature phase: LOCAL partials)
  float wc[8][KC];      // per-wave count partials
  float redf[8];
  int   redi[8];
  int   far5[KC];
};

// ---------- block reductions (512 threads = 8 waves) ----------
__device__ __forceinline__ void block_argmax(float v, int i, Sm& sm, float& bv, int& bi) {
  #pragma unroll
  for (int off = 32; off; off >>= 1) {
    float v2 = __shfl_xor(v, off);
    int   i2 = __shfl_xor(i, off);
    if (v2 > v || (v2 == v && i2 < i)) { v = v2; i = i2; }
  }
  __syncthreads();
  if ((threadIdx.x & 63) == 0) { sm.redf[threadIdx.x >> 6] = v; sm.redi[threadIdx.x >> 6] = i; }
  __syncthreads();
  bv = sm.redf[0]; bi = sm.redi[0];
  #pragma unroll
  for (int g = 1; g < 8; g++) {
    float v2 = sm.redf[g]; int i2 = sm.redi[g];
    if (v2 > bv || (v2 == bv && i2 < bi)) { bv = v2; bi = i2; }
  }
}

__device__ __forceinline__ float block_sum(float v, Sm& sm) {
  #pragma unroll
  for (int off = 32; off; off >>= 1) v += __shfl_xor(v, off);
  __syncthreads();
  if ((threadIdx.x & 63) == 0) sm.redf[threadIdx.x >> 6] = v;
  __syncthreads();
  float s = 0.f;
  #pragma unroll
  for (int g = 0; g < 8; g++) s += sm.redf[g];
  return s;  // identical in all threads
}

__device__ __forceinline__ void reduce_counts(Sm& sm, float cn[KC]) {
  const int w = threadIdx.x >> 6, l = threadIdx.x & 63;
  #pragma unroll
  for (int k = 0; k < KC; k++) {
    float s = cn[k];
    #pragma unroll
    for (int off = 32; off; off >>= 1) s += __shfl_xor(s, off);
    cn[k] = s;
  }
  __syncthreads();
  if (l == 0) {
    #pragma unroll
    for (int k = 0; k < KC; k++) sm.wc[w][k] = cn[k];
  }
  __syncthreads();
  if (threadIdx.x == 0) {
    #pragma unroll
    for (int k = 0; k < KC; k++) {
      float s = 0.f;
      #pragma unroll
      for (int g = 0; g < 8; g++) s += sm.wc[g][k];
      sm.cnt[k] = s;
    }
  }
  __syncthreads();
}

__device__ void top5(Sm& sm, float* mdbuf) {   // position-phase (2048-wide) top5
  for (int r5 = 0; r5 < KC; r5++) {
    float lv = -1.f; int li = 0x7fffffff;
    #pragma unroll
    for (int r = 0; r < 4; r++) {
      const int i = 4 * threadIdx.x + r;
      const float v = mdbuf[i];
      if (v > lv) { lv = v; li = i; }
    }
    float bv; int bi;
    block_argmax(lv, li, sm, bv, bi);
    if (threadIdx.x == 0) { sm.far5[r5] = bi; mdbuf[bi] = -2.f; }
    __syncthreads();
  }
}

// ---------- distributed kmeans: local assignment over LPTS points ----------
__device__ void assign3_local(Sm& sm, const float* feaT, int base) {
  const int tid = threadIdx.x;
  float cn[KC] = {0.f, 0.f, 0.f, 0.f, 0.f};
  if (tid < LPTS) {
    const float x0 = feaT[0 * NS + base + tid];
    const float x1 = feaT[1 * NS + base + tid];
    const float x2 = feaT[2 * NS + base + tid];
    float best = FLT_MAX; int bk = 0;
    #pragma unroll
    for (int k = 0; k < KC; k++) {
      const float d0 = x0 - sm.c3[k][0];
      const float d1 = x1 - sm.c3[k][1];
      const float d2 = x2 - sm.c3[k][2];
      const float s = d0 * d0 + d1 * d1 + d2 * d2;
      if (s < best) { best = s; bk = k; }
    }
    sm.idx[tid] = bk;
    cn[bk] = 1.f;
  }
  reduce_counts(sm, cn);   // sm.cnt = LOCAL counts (published in A)
}

__device__ void assign_full_local(Sm& sm, const float* feaT, int base) {
  const int tid = threadIdx.x;
  float cn[KC] = {0.f, 0.f, 0.f, 0.f, 0.f};
  if (tid < LPTS) {
    float dot[KC] = {0.f, 0.f, 0.f, 0.f, 0.f};
    for (int j = 0; j < CD; j++) {
      const float x = feaT[(size_t)j * NS + base + tid];
      #pragma unroll
      for (int k = 0; k < KC; k++) dot[k] += x * sm.cm[k][j];
    }
    float best = dot[0] - sm.cc2h[0]; int bk = 0;
    #pragma unroll
    for (int k = 1; k < KC; k++) {
      const float s = dot[k] - sm.cc2h[k];
      if (s > best) { best = s; bk = k; }
    }
    sm.idx[tid] = bk;
    cn[bk] = 1.f;
  }
  reduce_counts(sm, cn);
}

// ---------- distributed kmeans iteration core (round-11-verified) ----------
__device__ float iter_core(Sm& sm, float* wbuf, float* mdbuf,
                           const float* fea_all, const float* feaT,
                           float* Apay, unsigned* Aflag, float* Cpay, unsigned* Cflag,
                           int base, int sub, unsigned n) {
  const int tid = threadIdx.x, w = tid >> 6, l = tid & 63;
  float4 acc[KC];
  #pragma unroll
  for (int k = 0; k < KC; k++) acc[k] = make_float4(0.f, 0.f, 0.f, 0.f);
  #pragma unroll 4
  for (int ii = 0; ii < 32; ii++) {
    const int li = (w << 5) + ii;
    const int k = __builtin_amdgcn_readfirstlane(sm.idx[li]);
    const float4 v = *(const float4*)&fea_all[(size_t)sm.sel[base + li] * CD + 4 * l];
    switch (k) {
      case 0: acc[0].x += v.x; acc[0].y += v.y; acc[0].z += v.z; acc[0].w += v.w; break;
      case 1: acc[1].x += v.x; acc[1].y += v.y; acc[1].z += v.z; acc[1].w += v.w; break;
      case 2: acc[2].x += v.x; acc[2].y += v.y; acc[2].z += v.z; acc[2].w += v.w; break;
      case 3: acc[3].x += v.x; acc[3].y += v.y; acc[3].z += v.z; acc[3].w += v.w; break;
      default: acc[4].x += v.x; acc[4].y += v.y; acc[4].z += v.z; acc[4].w += v.w; break;
    }
  }
  #pragma unroll
  for (int k = 0; k < KC; k++) *(float4*)&wbuf[(w * KC + k) * CD + 4 * l] = acc[k];
  __syncthreads();
  // publish A = {local counts[5], local sums[1280]}
  float* myA = Apay + sub * APAY_N;
  for (int e = tid; e < APAY_N; e += TPB) {
    float s;
    if (e < KC) s = sm.cnt[e];
    else {
      s = 0.f;
      #pragma unroll
      for (int g = 0; g < 8; g++) s += wbuf[g * (KC * CD) + (e - KC)];
    }
    myA[e] = s;
  }
  __threadfence();
  __syncthreads();
  if (tid == 0) __hip_atomic_store(&Aflag[sub], n, __ATOMIC_RELEASE, __HIP_MEMORY_SCOPE_AGENT);
  if (w == 0 && l < NB_K) {
    while (__hip_atomic_load(&Aflag[l], __ATOMIC_ACQUIRE, __HIP_MEMORY_SCOPE_AGENT) != n)
      __builtin_amdgcn_s_sleep(1);
  }
  __syncthreads();
  // reduce A (redundant, identical everywhere); b ascending = points ascending
  float cntk[KC];
  #pragma unroll
  for (int k = 0; k < KC; k++) {
    float s = 0.f;
    for (int b = 0; b < NB_K; b++) s += Apay[b * APAY_N + k];
    cntk[k] = s;
  }
  for (int e = tid; e < KC * CD; e += TPB) {
    float s = 0.f;
    for (int b = 0; b < NB_K; b++) s += Apay[b * APAY_N + KC + e];
    (&sm.cm[0][0])[e] = s / fmaxf(cntk[e >> 8], 1.f);
  }
  __syncthreads();
  // local sse partial over first 3 feature dims (pre-fixup cm)
  float contrib = 0.f;
  if (tid < LPTS) {
    const float x0 = feaT[0 * NS + base + tid];
    const float x1 = feaT[1 * NS + base + tid];
    const float x2 = feaT[2 * NS + base + tid];
    const int k = sm.idx[tid];
    const float d0 = x0 - sm.cm[k][0], d1 = x1 - sm.cm[k][1], d2 = x2 - sm.cm[k][2];
    contrib = d0 * d0 + d1 * d1 + d2 * d2;
  }
  const float lps = block_sum(contrib, sm);
  // empty-cluster metric + local top5 (rare; nmask identical across blocks)
  int nmask = 0;
  #pragma unroll
  for (int k = 0; k < KC; k++) nmask |= (cntk[k] == 0.f) ? (1 << k) : 0;
  float f5v[KC] = {0.f, 0.f, 0.f, 0.f, 0.f};
  int   f5i[KC] = {0, 0, 0, 0, 0};
  if (nmask) {
    if (tid < LPTS) {
      float dd[KC] = {0.f, 0.f, 0.f, 0.f, 0.f};
      for (int j = 0; j < CD; j++) {
        const float x = feaT[(size_t)j * NS + base + tid];
        #pragma unroll
        for (int k = 0; k < KC; k++) { const float d = x - sm.cm[k][j]; dd[k] += d * d; }
      }
      float s = 0.f;
      #pragma unroll
      for (int k = 0; k < KC; k++)
        if (cntk[k] > 0.f) s += sqrtf(fmaxf(dd[k], 0.f) + 1e-12f);
      mdbuf[tid] = s;
    }
    __syncthreads();
    for (int r5 = 0; r5 < KC; r5++) {
      const float lv = (tid < LPTS) ? mdbuf[tid] : -1.f;
      const int   li = (tid < LPTS) ? (base + tid) : 0x7fffffff;
      float bv; int bi;
      block_argmax(lv, li, sm, bv, bi);
      f5v[r5] = bv; f5i[r5] = bi;           // identical in all threads
      if (tid < LPTS && base + tid == bi) mdbuf[tid] = -2.f;
      __syncthreads();
    }
  }
  // publish C = {psum, top5 values, top5 global indices (bitcast)}
  float* myC = Cpay + sub * 16;
  if (tid == 0) {
    myC[0] = lps;
    #pragma unroll
    for (int r = 0; r < KC; r++) { myC[1 + r] = f5v[r]; myC[6 + r] = __int_as_float(f5i[r]); }
  }
  __threadfence();
  __syncthreads();
  if (tid == 0) __hip_atomic_store(&Cflag[sub], n, __ATOMIC_RELEASE, __HIP_MEMORY_SCOPE_AGENT);
  if (w == 0 && l < NB_K) {
    while (__hip_atomic_load(&Cflag[l], __ATOMIC_ACQUIRE, __HIP_MEMORY_SCOPE_AGENT) != n)
      __builtin_amdgcn_s_sleep(1);
  }
  __syncthreads();
  // read C: sse; merged exact top5 (value desc, index asc == lax.top_k) + fixup
  float ps = 0.f;
  for (int b = 0; b < NB_K; b++) ps += Cpay[b * 16];
  const float sse = sqrtf(ps);
  if (nmask) {
    unsigned long long used = 0ull;
    int farg[KC];
    for (int r5 = 0; r5 < KC; r5++) {
      float bv = -3.f; int bi = 0x7fffffff; int bs = 0;
      for (int s = 0; s < NB_K * KC; s++) {
        if (used & (1ull << s)) continue;
        const float v = Cpay[(s / KC) * 16 + 1 + (s % KC)];
        const int   i = __float_as_int(Cpay[(s / KC) * 16 + 6 + (s % KC)]);
        if (v > bv || (v == bv && i < bi)) { bv = v; bi = i; bs = s; }
      }
      used |= (1ull << bs);
      farg[r5] = bi;
    }
    int cum = 0;
    for (int k = 0; k < KC; k++) {     // uniform across threads and blocks
      if (cntk[k] == 0.f) {
        const int rk = (cum < KC) ? cum : (KC - 1);
        const int row = sm.sel[farg[rk]];
        for (int d = tid; d < CD; d += TPB) sm.cm[k][d] = fea_all[(size_t)row * CD + d];
        cum++;
      }
    }
    __syncthreads();
  }
  // cc2h (after fixup, for next assignment)
  if (tid < KC * 64) {
    const float4 c = *(const float4*)&sm.cm[w][4 * l];
    float s = c.x * c.x + c.y * c.y + c.z * c.z + c.w * c.w;
    #pragma unroll
    for (int off = 32; off; off >>= 1) s += __shfl_xor(s, off);
    if (l == 0) sm.cc2h[w] = 0.5f * s;
  }
  __syncthreads();
  return sse;
}

// ---------- FPS kernel: 4 blocks/branch x 1024 threads ----------
// Round-14: halve the sync agents (round-12 failure-tree lever). 8192 pts/block,
// still 8 pts/thread -> 32 persistent VGPRs (round-6 verified this footprint at
// 1024 threads: VGPR 52, no scratch). Round-12 cand layout RESTORED ([t][sub]:
// round-13 transpose cost +3%, FETCH 2.9->10.7MB — shared line is read-efficient).
// 4 writers/line instead of 8; poll merges 4 slots. XCD grouping br=blockIdx&3:
// branch b's blocks {b,b+4,b+8,b+12} land on 2 XCDs under round-robin dispatch.
// Packing unchanged: u64 = bit63|fbits<<32|(0xFFFFFFFF-idx); u64-max == (max
// value, min index) == jnp.argmax first-occurrence. Fresh per-t slots (memset).
__global__ __launch_bounds__(TPB_F) void fps_kernel(const float* __restrict__ pfirst,
                                                    const float* __restrict__ psec,
                                                    int* __restrict__ sel_base,
                                                    unsigned long long* __restrict__ cand) {
  const int br = blockIdx.x & 3, sub = blockIdx.x >> 2;   // XCD-grouped mapping
  const float* pos = ((br < 2) ? pfirst : psec) + (size_t)(br & 1) * N_PTS * 3;
  int* selg = sel_base + (size_t)br * NS;
  unsigned long long* mycand = cand + (size_t)br * NS * NB_F;  // [t][sub] within branch
  __shared__ float redf[16];
  __shared__ int   redi[16];
  __shared__ int   winLDS;
  const int tid = threadIdx.x, w = tid >> 6, l = tid & 63;
  const int base = sub * 8192;

  float px[8], py[8], pz[8], dd[8];          // 32 registers, static indices only
  #pragma unroll
  for (int k = 0; k < 8; k++) {
    const int p = base + tid + k * TPB_F;
    px[k] = pos[3 * p]; py[k] = pos[3 * p + 1]; pz[k] = pos[3 * p + 2];
    dd[k] = 1e10f;
  }
  if (sub == 0 && tid == 0) selg[0] = 0;
  float lx = pos[0], ly = pos[1], lz = pos[2];

  for (int t = 1; t < NS; t++) {
    float bv = -1.f; int bi = 0x7fffffff;
    #pragma unroll
    for (int k = 0; k < 8; k++) {
      const float dx = px[k] - lx, dy = py[k] - ly, dz = pz[k] - lz;
      const float dist = dx * dx + dy * dy + dz * dz;
      dd[k] = fminf(dd[k], dist);
      if (dd[k] > bv) { bv = dd[k]; bi = base + tid + k * TPB_F; }
    }
    const int myi = bi;
    // wave-level (value desc, index asc) argmax
    #pragma unroll
    for (int off = 32; off; off >>= 1) {
      const float v2 = __shfl_xor(bv, off);
      const int   i2 = __shfl_xor(bi, off);
      if (v2 > bv || (v2 == bv && i2 < bi)) { bv = v2; bi = i2; }
    }
    // unique wave-winner lane publishes to LDS (per-lane indices disjoint)
    if (myi == bi) { redf[w] = bv; redi[w] = bi; }
    __syncthreads();
    // wave 0 only: 16-slot shuffle block-reduce -> publish -> poll 4 -> LDS bcast
    if (w == 0) {
      float cv = -1.f; int ci = 0x7fffffff;
      if (l < 16) { cv = redf[l]; ci = redi[l]; }
      #pragma unroll
      for (int off = 8; off; off >>= 1) {
        const float v2 = __shfl_xor(cv, off);
        const int   i2 = __shfl_xor(ci, off);
        if (v2 > cv || (v2 == cv && i2 < ci)) { cv = v2; ci = i2; }
      }
      if (l == 0) {
        const unsigned long long pk = (1ULL << 63)
            | ((unsigned long long)__float_as_uint(cv) << 32)
            | (unsigned long long)(0xFFFFFFFFu - (unsigned)ci);
        __hip_atomic_store(&mycand[(size_t)t * NB_F + sub], pk,
                           __ATOMIC_RELEASE, __HIP_MEMORY_SCOPE_AGENT);
      }
      unsigned long long pk = 0ULL;
      if (l < NB_F) {
        pk = __hip_atomic_load(&mycand[(size_t)t * NB_F + l],
                               __ATOMIC_ACQUIRE, __HIP_MEMORY_SCOPE_AGENT);
        while (pk == 0ULL) {
          __builtin_amdgcn_s_sleep(1);
          pk = __hip_atomic_load(&mycand[(size_t)t * NB_F + l],
                                 __ATOMIC_ACQUIRE, __HIP_MEMORY_SCOPE_AGENT);
        }
      }
      #pragma unroll
      for (int off = 2; off; off >>= 1) {
        const unsigned long long o = __shfl_xor(pk, off, NB_F);
        pk = (o > pk) ? o : pk;
      }
      if (l == 0) {
        const int gi = (int)(0xFFFFFFFFu - (unsigned)(pk & 0xFFFFFFFFull));
        winLDS = gi;
        if (sub == 0) selg[t] = gi;
      }
    }
    __syncthreads();
    const int gbi = winLDS;
    lx = pos[3 * gbi]; ly = pos[3 * gbi + 1]; lz = pos[3 * gbi + 2];  // bcast, L1/L2-hit
  }
}

// ---------- distributed kmeans kernel: 8 blocks/branch x 512 threads (round-11) ----------
__global__ __launch_bounds__(TPB) void branch_kernel(const float* __restrict__ logits,
                                                     const float* __restrict__ logits1,
                                                     const float* __restrict__ pfirst,
                                                     const float* __restrict__ psec,
                                                     const int* __restrict__ sel_base,
                                                     float* __restrict__ feaT_base,
                                                     float* __restrict__ accum,
                                                     float* __restrict__ apay,
                                                     unsigned* __restrict__ aflag,
                                                     float* __restrict__ cpay,
                                                     unsigned* __restrict__ cflag) {
  const int br = blockIdx.x >> 3, sub = blockIdx.x & 7;
  const float* fea_all = ((br < 2) ? logits : logits1) + (size_t)(br & 1) * N_PTS * CD;
  const float* pos     = ((br < 2) ? pfirst : psec) + (size_t)(br & 1) * N_PTS * 3;
  const int* selg = sel_base + (size_t)br * NS;
  float* feaT = feaT_base + (size_t)br * NS * CD;
  float*    Apay  = apay  + (size_t)br * NB_K * APAY_N;
  unsigned* Aflag = aflag + br * NB_K;
  float*    Cpay  = cpay  + (size_t)br * NB_K * 16;
  unsigned* Cflag = cflag + br * NB_K;
  const int base = sub * LPTS;

  __shared__ Sm sm;
  extern __shared__ char dynraw[];
  const int tid = threadIdx.x, w = tid >> 6, l = tid & 63;

  for (int i = tid; i < NS; i += TPB) sm.sel[i] = selg[i];
  __syncthreads();

  // ================= gather sampled pos into LDS (full 2048, redundant) =========
  float* pos_s = (float*)dynraw;             // [NS*3] 0..24576
  float* stag  = (float*)(dynraw + 24576);   // [64][257] transpose staging
  float* wbuf  = (float*)(dynraw + 24576);   // 40960 B, reused after transpose
  float* mdbuf = (float*)(dynraw + 98304);   // [NS] (position) / [LPTS] (feature)
  for (int i = tid; i < NS; i += TPB) {
    const int s = sm.sel[i];
    pos_s[3 * i] = pos[3 * s]; pos_s[3 * i + 1] = pos[3 * s + 1]; pos_s[3 * i + 2] = pos[3 * s + 2];
  }

  // ================= gather + transpose OWN feature slice -> feaT ===============
  for (int tile = base; tile < base + LPTS; tile += 64) {
    __syncthreads();
    for (int rr = w; rr < 64; rr += 8) {
      const int srow = sm.sel[tile + rr];
      const float4 v = *(const float4*)&fea_all[(size_t)srow * CD + 4 * l];
      float* dst = &stag[rr * 257 + 4 * l];
      dst[0] = v.x; dst[1] = v.y; dst[2] = v.z; dst[3] = v.w;
    }
    __syncthreads();
    for (int dd = 0; dd < 32; dd++) {
      const int dim = w * 32 + dd;
      feaT[(size_t)dim * NS + tile + l] = stag[l * 257 + dim];
    }
  }
  __syncthreads();

  // ================= initial centroids (greedy, positions; redundant) ===========
  if (tid == 0) { sm.c3[0][0] = pos_s[0]; sm.c3[0][1] = pos_s[1]; sm.c3[0][2] = pos_s[2]; }
  __syncthreads();
  for (int k = 1; k < KC; k++) {
    float lv = -1.f; int li = 0x7fffffff;
    #pragma unroll
    for (int r = 0; r < 4; r++) {
      const int i = 4 * tid + r;
      const float x = pos_s[3 * i], y = pos_s[3 * i + 1], z = pos_s[3 * i + 2];
      float a = 0.f;
      for (int j = 0; j < k; j++) {
        const float dx = x - sm.c3[j][0], dy = y - sm.c3[j][1], dz = z - sm.c3[j][2];
        a += dx * dx + dy * dy + dz * dz;
      }
      if (a > lv) { lv = a; li = i; }
    }
    float bv; int bi;
    block_argmax(lv, li, sm, bv, bi);
    if (tid == 0) { sm.c3[k][0] = pos_s[3 * bi]; sm.c3[k][1] = pos_s[3 * bi + 1]; sm.c3[k][2] = pos_s[3 * bi + 2]; }
    __syncthreads();
  }

  // ================= one kmeans step on positions (full 2048, redundant) ========
  {
    float a3[KC][3]; float cn[KC];
    #pragma unroll
    for (int k = 0; k < KC; k++) { a3[k][0] = 0.f; a3[k][1] = 0.f; a3[k][2] = 0.f; cn[k] = 0.f; }
    #pragma unroll
    for (int r = 0; r < 4; r++) {
      const int i = 4 * tid + r;
      const float x = pos_s[3 * i], y = pos_s[3 * i + 1], z = pos_s[3 * i + 2];
      float best = FLT_MAX; int bk = 0;
      #pragma unroll
      for (int k = 0; k < KC; k++) {
        const float dx = x - sm.c3[k][0], dy = y - sm.c3[k][1], dz = z - sm.c3[k][2];
        const float s = dx * dx + dy * dy + dz * dz;
        if (s < best) { best = s; bk = k; }
      }
      sm.idx[i] = bk;
      #pragma unroll
      for (int k = 0; k < KC; k++) {
        const float m = (bk == k) ? 1.f : 0.f;
        a3[k][0] += m * x; a3[k][1] += m * y; a3[k][2] += m * z; cn[k] += m;
      }
    }
    reduce_counts(sm, cn);
    #pragma unroll
    for (int k = 0; k < KC; k++) {
      #pragma unroll
      for (int c = 0; c < 3; c++) {
        float s = a3[k][c];
        #pragma unroll
        for (int off = 32; off; off >>= 1) s += __shfl_xor(s, off);
        a3[k][c] = s;
      }
    }
    __syncthreads();
    if (l == 0) {
      #pragma unroll
      for (int k = 0; k < KC; k++) {
        wbuf[w * 16 + k * 3 + 0] = a3[k][0];
        wbuf[w * 16 + k * 3 + 1] = a3[k][1];
        wbuf[w * 16 + k * 3 + 2] = a3[k][2];
      }
    }
    __syncthreads();
    if (tid == 0) {
      for (int k = 0; k < KC; k++)
        for (int c = 0; c < 3; c++) {
          float s = 0.f;
          for (int g = 0; g < 8; g++) s += wbuf[g * 16 + k * 3 + c];
          sm.c3[k][c] = s / fmaxf(sm.cnt[k], 1.f);
        }
    }
    __syncthreads();
  }
  float psum = 0.f;
  #pragma unroll
  for (int r = 0; r < 4; r++) {
    const int i = 4 * tid + r; const int k = sm.idx[i];
    const float dx = pos_s[3 * i] - sm.c3[k][0];
    const float dy = pos_s[3 * i + 1] - sm.c3[k][1];
    const float dz = pos_s[3 * i + 2] - sm.c3[k][2];
    psum += dx * dx + dy * dy + dz * dz;
  }
  const float sse_n = sqrtf(block_sum(psum, sm));
  {  // empty-cluster fixup (positions, full 2048, redundant)
    int nmask = 0;
    #pragma unroll
    for (int k = 0; k < KC; k++) nmask |= (sm.cnt[k] == 0.f) ? (1 << k) : 0;
    if (nmask) {
      #pragma unroll
      for (int r = 0; r < 4; r++) {
        const int i = 4 * tid + r;
        const float x = pos_s[3 * i], y = pos_s[3 * i + 1], z = pos_s[3 * i + 2];
        float s = 0.f;
        for (int k = 0; k < KC; k++) {
          if (sm.cnt[k] > 0.f) {
            const float dx = x - sm.c3[k][0], dy = y - sm.c3[k][1], dz = z - sm.c3[k][2];
            s += sqrtf(dx * dx + dy * dy + dz * dz + 1e-12f);
          }
        }
        mdbuf[i] = s;
      }
      __syncthreads();
      top5(sm, mdbuf);
      if (tid == 0) {
        int cum = 0;
        for (int k = 0; k < KC; k++) {
          if (sm.cnt[k] == 0.f) {
            const int rk = (cum < KC) ? cum : (KC - 1);
            const int src = sm.far5[rk];
            sm.c3[k][0] = pos_s[3 * src]; sm.c3[k][1] = pos_s[3 * src + 1]; sm.c3[k][2] = pos_s[3 * src + 2];
            cum++;
          }
        }
      }
      __syncthreads();
    }
  }

  // ================= distributed kmeans on features =================
  assign3_local(sm, feaT, base);
  float sse_fin = iter_core(sm, wbuf, mdbuf, fea_all, feaT,
                            Apay, Aflag, Cpay, Cflag, base, sub, 1u);
  float sse_pre = sse_fin;
  bool done = fabsf(sse_fin) < TOLV;
  for (int it = 1; it < MAX_IT && !done; it++) {
    assign_full_local(sm, feaT, base);
    const float s2 = iter_core(sm, wbuf, mdbuf, fea_all, feaT,
                               Apay, Aflag, Cpay, Cflag, base, sub, (unsigned)(it + 1));
    sse_fin = s2;
    done = fabsf(s2 - sse_pre) < TOLV;
    sse_pre = s2;
  }
  if (sub == 0 && tid == 0) atomicAdd(&accum[1], sse_n + sse_fin);
}

// ---------- global point loss (cosine similarity) ----------
__global__ __launch_bounds__(256) void gp_kernel(const float* __restrict__ A,
                                                 const float* __restrict__ B,
                                                 float* __restrict__ accum) {
  __shared__ float bacc;
  const int tid = threadIdx.x, l = tid & 63, w = tid >> 6;
  if (tid == 0) bacc = 0.f;
  __syncthreads();
  const int gw = blockIdx.x * 4 + w;
  const int NW = gridDim.x * 4;
  float lsum = 0.f;
  for (int p = gw; p < 65536; p += NW) {
    const float4 a = *(const float4*)&A[(size_t)p * CD + 4 * l];
    const float4 b = *(const float4*)&B[(size_t)p * CD + 4 * l];
    float ab = a.x * b.x + a.y * b.y + a.z * b.z + a.w * b.w;
    float aa = a.x * a.x + a.y * a.y + a.z * a.z + a.w * a.w;
    float bb = b.x * b.x + b.y * b.y + b.z * b.z + b.w * b.w;
    #pragma unroll
    for (int off = 32; off; off >>= 1) {
      ab += __shfl_xor(ab, off); aa += __shfl_xor(aa, off); bb += __shfl_xor(bb, off);
    }
    if (l == 0) lsum += ab / fmaxf(sqrtf(aa) * sqrtf(bb), 1e-8f);
  }
  if (l == 0) atomicAdd(&bacc, lsum);
  __syncthreads();
  if (tid == 0) atomicAdd(&accum[0], bacc);
}

__global__ void fin_kernel(const float* __restrict__ accum, float* __restrict__ out) {
  out[0] = -accum[0] / 65536.0f + accum[1];
}

extern "C" void kernel_launch(void* const* d_in, const int* in_sizes, int n_in,
                              void* d_out, int out_size, void* d_ws, size_t ws_size,
                              hipStream_t stream) {
  const float* logits  = (const float*)d_in[0];
  const float* logits1 = (const float*)d_in[1];
  const float* pfirst  = (const float*)d_in[2];
  const float* psec    = (const float*)d_in[3];
  float* out = (float*)d_out;
  float* wsf = (float*)d_ws;
  // workspace layout (float offsets):
  float* accum = wsf;                                          // [0..16)
  int* selg = (int*)(wsf + 16);                                // 4*NS ints -> ends @8208
  unsigned long long* cand = (unsigned long long*)(wsf + 8208);  // byte 32832 %8==0;
                                                               // 4*NS*NB_F u64 = 32768 fl
  unsigned* aflag = (unsigned*)(wsf + 40976);                  // after cand
  unsigned* cflag = (unsigned*)(wsf + 41008);
  float* apay = wsf + 41040;                                   // 4*8*1285 = 41120 floats
  float* cpay = wsf + 82160;                                   // 4*8*16 = 512 floats
  float* feaT = wsf + 82672;                                   // byte 330688 %16==0; 8 MB

  static std::once_flag once;
  std::call_once(once, []() {
    (void)hipFuncSetAttribute((const void*)branch_kernel,
                              hipFuncAttributeMaxDynamicSharedMemorySize, DYN_K);
    (void)hipGetLastError();
  });

  // zero accum + selg + cand + flags (fresh cand slots + flag seqs start at 0 -> poll ==n
  // with n>=1 is ABA-free; payload regions need no zeroing, guarded by flags)
  (void)hipMemsetAsync(wsf, 0, (size_t)41040 * 4, stream);
  gp_kernel<<<1024, 256, 0, stream>>>(logits, logits1, accum);
  fps_kernel<<<4 * NB_F, TPB_F, 0, stream>>>(pfirst, psec, selg, cand);
  branch_kernel<<<4 * NB_K, TPB, DYN_K, stream>>>(logits, logits1, pfirst, psec,
                                                  selg, feaT, accum,
                                                  apay, aflag, cpay, cflag);
  fin_kernel<<<1, 1, 0, stream>>>(accum, out);
}

// Round 15
// 6304.115 us; speedup vs baseline: 1.0186x; 1.0186x over previous
//
#include <hip/hip_runtime.h>
#include <math.h>
#include <float.h>
#include <mutex>

// Problem constants (match reference)
#define N_PTS  32768
#define NS     2048      // N_PTS/16 downsample
#define CD     256
#define KC     5
#define TPB    512       // kmeans kernel threads/block
#define TPB_F  512       // FPS kernel threads/block
#define NB_F   8         // FPS blocks per branch
#define NB_K   8         // kmeans blocks per branch (distributed kmeans)
#define LPTS   256       // NS/NB_K local sampled points per kmeans block
#define APAY_N 1285      // A-payload floats: counts[5] + sums[5*256]
#define MAX_IT 100
#define TOLV   1e-3f
#define DYN_K  131072    // kmeans dyn LDS: pos_s(24576) + stag/wbuf + mdbuf(@98304)

struct Sm {
  int   sel[NS];        // FPS-selected indices into the 32768 points (full copy)
  int   idx[NS];        // cluster assignment (position phase: 2048; feature phase: local 256)
  float cm[KC][CD];     // feature-space centroids (globally reduced, identical per block)
  float cc2h[KC];       // 0.5*|c|^2
  float c3[KC][3];      // position-space centroids
  float cnt[KC];        // counts (position phase: global; feature phase: LOCAL partials)
  float wc[8][KC];      // per-wave count partials
  float redf[8];
  int   redi[8];
  int   far5[KC];
};

// ---------- block reductions (512 threads = 8 waves) ----------
__device__ __forceinline__ void block_argmax(float v, int i, Sm& sm, float& bv, int& bi) {
  #pragma unroll
  for (int off = 32; off; off >>= 1) {
    float v2 = __shfl_xor(v, off);
    int   i2 = __shfl_xor(i, off);
    if (v2 > v || (v2 == v && i2 < i)) { v = v2; i = i2; }
  }
  __syncthreads();
  if ((threadIdx.x & 63) == 0) { sm.redf[threadIdx.x >> 6] = v; sm.redi[threadIdx.x >> 6] = i; }
  __syncthreads();
  bv = sm.redf[0]; bi = sm.redi[0];
  #pragma unroll
  for (int g = 1; g < 8; g++) {
    float v2 = sm.redf[g]; int i2 = sm.redi[g];
    if (v2 > bv || (v2 == bv && i2 < bi)) { bv = v2; bi = i2; }
  }
}

__device__ __forceinline__ float block_sum(float v, Sm& sm) {
  #pragma unroll
  for (int off = 32; off; off >>= 1) v += __shfl_xor(v, off);
  __syncthreads();
  if ((threadIdx.x & 63) == 0) sm.redf[threadIdx.x >> 6] = v;
  __syncthreads();
  float s = 0.f;
  #pragma unroll
  for (int g = 0; g < 8; g++) s += sm.redf[g];
  return s;  // identical in all threads
}

__device__ __forceinline__ void reduce_counts(Sm& sm, float cn[KC]) {
  const int w = threadIdx.x >> 6, l = threadIdx.x & 63;
  #pragma unroll
  for (int k = 0; k < KC; k++) {
    float s = cn[k];
    #pragma unroll
    for (int off = 32; off; off >>= 1) s += __shfl_xor(s, off);
    cn[k] = s;
  }
  __syncthreads();
  if (l == 0) {
    #pragma unroll
    for (int k = 0; k < KC; k++) sm.wc[w][k] = cn[k];
  }
  __syncthreads();
  if (threadIdx.x == 0) {
    #pragma unroll
    for (int k = 0; k < KC; k++) {
      float s = 0.f;
      #pragma unroll
      for (int g = 0; g < 8; g++) s += sm.wc[g][k];
      sm.cnt[k] = s;
    }
  }
  __syncthreads();
}

__device__ void top5(Sm& sm, float* mdbuf) {   // position-phase (2048-wide) top5
  for (int r5 = 0; r5 < KC; r5++) {
    float lv = -1.f; int li = 0x7fffffff;
    #pragma unroll
    for (int r = 0; r < 4; r++) {
      const int i = 4 * threadIdx.x + r;
      const float v = mdbuf[i];
      if (v > lv) { lv = v; li = i; }
    }
    float bv; int bi;
    block_argmax(lv, li, sm, bv, bi);
    if (threadIdx.x == 0) { sm.far5[r5] = bi; mdbuf[bi] = -2.f; }
    __syncthreads();
  }
}

// ---------- distributed kmeans: local assignment over LPTS points ----------
__device__ void assign3_local(Sm& sm, const float* feaT, int base) {
  const int tid = threadIdx.x;
  float cn[KC] = {0.f, 0.f, 0.f, 0.f, 0.f};
  if (tid < LPTS) {
    const float x0 = feaT[0 * NS + base + tid];
    const float x1 = feaT[1 * NS + base + tid];
    const float x2 = feaT[2 * NS + base + tid];
    float best = FLT_MAX; int bk = 0;
    #pragma unroll
    for (int k = 0; k < KC; k++) {
      const float d0 = x0 - sm.c3[k][0];
      const float d1 = x1 - sm.c3[k][1];
      const float d2 = x2 - sm.c3[k][2];
      const float s = d0 * d0 + d1 * d1 + d2 * d2;
      if (s < best) { best = s; bk = k; }
    }
    sm.idx[tid] = bk;
    cn[bk] = 1.f;
  }
  reduce_counts(sm, cn);   // sm.cnt = LOCAL counts (published in A)
}

__device__ void assign_full_local(Sm& sm, const float* feaT, int base) {
  const int tid = threadIdx.x;
  float cn[KC] = {0.f, 0.f, 0.f, 0.f, 0.f};
  if (tid < LPTS) {
    float dot[KC] = {0.f, 0.f, 0.f, 0.f, 0.f};
    for (int j = 0; j < CD; j++) {
      const float x = feaT[(size_t)j * NS + base + tid];
      #pragma unroll
      for (int k = 0; k < KC; k++) dot[k] += x * sm.cm[k][j];
    }
    float best = dot[0] - sm.cc2h[0]; int bk = 0;
    #pragma unroll
    for (int k = 1; k < KC; k++) {
      const float s = dot[k] - sm.cc2h[k];
      if (s > best) { best = s; bk = k; }
    }
    sm.idx[tid] = bk;
    cn[bk] = 1.f;
  }
  reduce_counts(sm, cn);
}

// ---------- distributed kmeans iteration core (round-11-verified) ----------
__device__ float iter_core(Sm& sm, float* wbuf, float* mdbuf,
                           const float* fea_all, const float* feaT,
                           float* Apay, unsigned* Aflag, float* Cpay, unsigned* Cflag,
                           int base, int sub, unsigned n) {
  const int tid = threadIdx.x, w = tid >> 6, l = tid & 63;
  float4 acc[KC];
  #pragma unroll
  for (int k = 0; k < KC; k++) acc[k] = make_float4(0.f, 0.f, 0.f, 0.f);
  #pragma unroll 4
  for (int ii = 0; ii < 32; ii++) {
    const int li = (w << 5) + ii;
    const int k = __builtin_amdgcn_readfirstlane(sm.idx[li]);
    const float4 v = *(const float4*)&fea_all[(size_t)sm.sel[base + li] * CD + 4 * l];
    switch (k) {
      case 0: acc[0].x += v.x; acc[0].y += v.y; acc[0].z += v.z; acc[0].w += v.w; break;
      case 1: acc[1].x += v.x; acc[1].y += v.y; acc[1].z += v.z; acc[1].w += v.w; break;
      case 2: acc[2].x += v.x; acc[2].y += v.y; acc[2].z += v.z; acc[2].w += v.w; break;
      case 3: acc[3].x += v.x; acc[3].y += v.y; acc[3].z += v.z; acc[3].w += v.w; break;
      default: acc[4].x += v.x; acc[4].y += v.y; acc[4].z += v.z; acc[4].w += v.w; break;
    }
  }
  #pragma unroll
  for (int k = 0; k < KC; k++) *(float4*)&wbuf[(w * KC + k) * CD + 4 * l] = acc[k];
  __syncthreads();
  // publish A = {local counts[5], local sums[1280]}
  float* myA = Apay + sub * APAY_N;
  for (int e = tid; e < APAY_N; e += TPB) {
    float s;
    if (e < KC) s = sm.cnt[e];
    else {
      s = 0.f;
      #pragma unroll
      for (int g = 0; g < 8; g++) s += wbuf[g * (KC * CD) + (e - KC)];
    }
    myA[e] = s;
  }
  __threadfence();
  __syncthreads();
  if (tid == 0) __hip_atomic_store(&Aflag[sub], n, __ATOMIC_RELEASE, __HIP_MEMORY_SCOPE_AGENT);
  if (w == 0 && l < NB_K) {
    while (__hip_atomic_load(&Aflag[l], __ATOMIC_ACQUIRE, __HIP_MEMORY_SCOPE_AGENT) != n)
      __builtin_amdgcn_s_sleep(1);
  }
  __syncthreads();
  // reduce A (redundant, identical everywhere); b ascending = points ascending
  float cntk[KC];
  #pragma unroll
  for (int k = 0; k < KC; k++) {
    float s = 0.f;
    for (int b = 0; b < NB_K; b++) s += Apay[b * APAY_N + k];
    cntk[k] = s;
  }
  for (int e = tid; e < KC * CD; e += TPB) {
    float s = 0.f;
    for (int b = 0; b < NB_K; b++) s += Apay[b * APAY_N + KC + e];
    (&sm.cm[0][0])[e] = s / fmaxf(cntk[e >> 8], 1.f);
  }
  __syncthreads();
  // local sse partial over first 3 feature dims (pre-fixup cm)
  float contrib = 0.f;
  if (tid < LPTS) {
    const float x0 = feaT[0 * NS + base + tid];
    const float x1 = feaT[1 * NS + base + tid];
    const float x2 = feaT[2 * NS + base + tid];
    const int k = sm.idx[tid];
    const float d0 = x0 - sm.cm[k][0], d1 = x1 - sm.cm[k][1], d2 = x2 - sm.cm[k][2];
    contrib = d0 * d0 + d1 * d1 + d2 * d2;
  }
  const float lps = block_sum(contrib, sm);
  // empty-cluster metric + local top5 (rare; nmask identical across blocks)
  int nmask = 0;
  #pragma unroll
  for (int k = 0; k < KC; k++) nmask |= (cntk[k] == 0.f) ? (1 << k) : 0;
  float f5v[KC] = {0.f, 0.f, 0.f, 0.f, 0.f};
  int   f5i[KC] = {0, 0, 0, 0, 0};
  if (nmask) {
    if (tid < LPTS) {
      float dd[KC] = {0.f, 0.f, 0.f, 0.f, 0.f};
      for (int j = 0; j < CD; j++) {
        const float x = feaT[(size_t)j * NS + base + tid];
        #pragma unroll
        for (int k = 0; k < KC; k++) { const float d = x - sm.cm[k][j]; dd[k] += d * d; }
      }
      float s = 0.f;
      #pragma unroll
      for (int k = 0; k < KC; k++)
        if (cntk[k] > 0.f) s += sqrtf(fmaxf(dd[k], 0.f) + 1e-12f);
      mdbuf[tid] = s;
    }
    __syncthreads();
    for (int r5 = 0; r5 < KC; r5++) {
      const float lv = (tid < LPTS) ? mdbuf[tid] : -1.f;
      const int   li = (tid < LPTS) ? (base + tid) : 0x7fffffff;
      float bv; int bi;
      block_argmax(lv, li, sm, bv, bi);
      f5v[r5] = bv; f5i[r5] = bi;           // identical in all threads
      if (tid < LPTS && base + tid == bi) mdbuf[tid] = -2.f;
      __syncthreads();
    }
  }
  // publish C = {psum, top5 values, top5 global indices (bitcast)}
  float* myC = Cpay + sub * 16;
  if (tid == 0) {
    myC[0] = lps;
    #pragma unroll
    for (int r = 0; r < KC; r++) { myC[1 + r] = f5v[r]; myC[6 + r] = __int_as_float(f5i[r]); }
  }
  __threadfence();
  __syncthreads();
  if (tid == 0) __hip_atomic_store(&Cflag[sub], n, __ATOMIC_RELEASE, __HIP_MEMORY_SCOPE_AGENT);
  if (w == 0 && l < NB_K) {
    while (__hip_atomic_load(&Cflag[l], __ATOMIC_ACQUIRE, __HIP_MEMORY_SCOPE_AGENT) != n)
      __builtin_amdgcn_s_sleep(1);
  }
  __syncthreads();
  // read C: sse; merged exact top5 (value desc, index asc == lax.top_k) + fixup
  float ps = 0.f;
  for (int b = 0; b < NB_K; b++) ps += Cpay[b * 16];
  const float sse = sqrtf(ps);
  if (nmask) {
    unsigned long long used = 0ull;
    int farg[KC];
    for (int r5 = 0; r5 < KC; r5++) {
      float bv = -3.f; int bi = 0x7fffffff; int bs = 0;
      for (int s = 0; s < NB_K * KC; s++) {
        if (used & (1ull << s)) continue;
        const float v = Cpay[(s / KC) * 16 + 1 + (s % KC)];
        const int   i = __float_as_int(Cpay[(s / KC) * 16 + 6 + (s % KC)]);
        if (v > bv || (v == bv && i < bi)) { bv = v; bi = i; bs = s; }
      }
      used |= (1ull << bs);
      farg[r5] = bi;
    }
    int cum = 0;
    for (int k = 0; k < KC; k++) {     // uniform across threads and blocks
      if (cntk[k] == 0.f) {
        const int rk = (cum < KC) ? cum : (KC - 1);
        const int row = sm.sel[farg[rk]];
        for (int d = tid; d < CD; d += TPB) sm.cm[k][d] = fea_all[(size_t)row * CD + d];
        cum++;
      }
    }
    __syncthreads();
  }
  // cc2h (after fixup, for next assignment)
  if (tid < KC * 64) {
    const float4 c = *(const float4*)&sm.cm[w][4 * l];
    float s = c.x * c.x + c.y * c.y + c.z * c.z + c.w * c.w;
    #pragma unroll
    for (int off = 32; off; off >>= 1) s += __shfl_xor(s, off);
    if (l == 0) sm.cc2h[w] = 0.5f * s;
  }
  __syncthreads();
  return sse;
}

// ---------- FPS kernel: 8 active blocks/branch, ALL ON ONE XCD ----------
// Round-15 hypothesis: the ~2.3us/iter chain is the cross-XCD release->acquire
// round-trip. Per-XCD L2 is the coherence point for its own CUs, so if all 8
// agents of a branch sit on ONE XCD, agent-scope atomics on their cand lines are
// serviced locally (no fabric coherence transitions). Under the round-robin
// blockIdx%8->XCD heuristic (supported by round-12's FETCH 10.1->2.9MB drop),
// launch 64 blocks: br = blockIdx&7 (the XCD), sub = blockIdx>>3; blocks with
// br>=4 exit immediately (32 dead dispatches, ~us). Branch b's 8 workers all have
// blockIdx%8 == b -> XCD b. Everything else byte-identical to round-12's verified
// 4743us kernel: [t][sub] cand layout (round-13 proved the shared line is
// read-efficient), winner-lane LDS publish + wave-0 shuffle reduce, wave-0-only
// poll, LDS broadcast, read-only pos[3*gbi] winner load.
// Packing: u64 = bit63|fbits<<32|(0xFFFFFFFF-idx); u64-max == (max value, min
// index) == jnp.argmax first-occurrence. Fresh per-t slots (memset per launch).
__global__ __launch_bounds__(TPB_F) void fps_kernel(const float* __restrict__ pfirst,
                                                    const float* __restrict__ psec,
                                                    int* __restrict__ sel_base,
                                                    unsigned long long* __restrict__ cand) {
  const int br = blockIdx.x & 7, sub = blockIdx.x >> 3;   // one XCD per branch
  if (br >= 4) return;                                    // 32 dead blocks exit
  const float* pos = ((br < 2) ? pfirst : psec) + (size_t)(br & 1) * N_PTS * 3;
  int* selg = sel_base + (size_t)br * NS;
  unsigned long long* mycand = cand + (size_t)br * NS * NB_F;  // [t][sub] within branch
  __shared__ float redf[8];
  __shared__ int   redi[8];
  __shared__ int   winLDS;
  const int tid = threadIdx.x, w = tid >> 6, l = tid & 63;
  const int base = sub * 4096;

  float px[8], py[8], pz[8], dd[8];          // 32 registers, static indices only
  #pragma unroll
  for (int k = 0; k < 8; k++) {
    const int p = base + tid + k * TPB_F;
    px[k] = pos[3 * p]; py[k] = pos[3 * p + 1]; pz[k] = pos[3 * p + 2];
    dd[k] = 1e10f;
  }
  if (sub == 0 && tid == 0) selg[0] = 0;
  float lx = pos[0], ly = pos[1], lz = pos[2];

  for (int t = 1; t < NS; t++) {
    float bv = -1.f; int bi = 0x7fffffff;
    #pragma unroll
    for (int k = 0; k < 8; k++) {
      const float dx = px[k] - lx, dy = py[k] - ly, dz = pz[k] - lz;
      const float dist = dx * dx + dy * dy + dz * dz;
      dd[k] = fminf(dd[k], dist);
      if (dd[k] > bv) { bv = dd[k]; bi = base + tid + k * TPB_F; }
    }
    const int myi = bi;
    // wave-level (value desc, index asc) argmax
    #pragma unroll
    for (int off = 32; off; off >>= 1) {
      const float v2 = __shfl_xor(bv, off);
      const int   i2 = __shfl_xor(bi, off);
      if (v2 > bv || (v2 == bv && i2 < bi)) { bv = v2; bi = i2; }
    }
    // unique wave-winner lane publishes to LDS (per-lane indices disjoint)
    if (myi == bi) { redf[w] = bv; redi[w] = bi; }
    __syncthreads();
    // wave 0 only: shuffle block-reduce -> publish -> poll -> LDS broadcast
    if (w == 0) {
      float cv = -1.f; int ci = 0x7fffffff;
      if (l < 8) { cv = redf[l]; ci = redi[l]; }
      #pragma unroll
      for (int off = 4; off; off >>= 1) {
        const float v2 = __shfl_xor(cv, off);
        const int   i2 = __shfl_xor(ci, off);
        if (v2 > cv || (v2 == cv && i2 < ci)) { cv = v2; ci = i2; }
      }
      if (l == 0) {
        const unsigned long long pk = (1ULL << 63)
            | ((unsigned long long)__float_as_uint(cv) << 32)
            | (unsigned long long)(0xFFFFFFFFu - (unsigned)ci);
        __hip_atomic_store(&mycand[(size_t)t * NB_F + sub], pk,
                           __ATOMIC_RELEASE, __HIP_MEMORY_SCOPE_AGENT);
      }
      unsigned long long pk = 0ULL;
      if (l < NB_F) {
        pk = __hip_atomic_load(&mycand[(size_t)t * NB_F + l],
                               __ATOMIC_ACQUIRE, __HIP_MEMORY_SCOPE_AGENT);
        while (pk == 0ULL) {
          __builtin_amdgcn_s_sleep(1);
          pk = __hip_atomic_load(&mycand[(size_t)t * NB_F + l],
                                 __ATOMIC_ACQUIRE, __HIP_MEMORY_SCOPE_AGENT);
        }
      }
      #pragma unroll
      for (int off = 4; off; off >>= 1) {
        const unsigned long long o = __shfl_xor(pk, off, NB_F);
        pk = (o > pk) ? o : pk;
      }
      if (l == 0) {
        const int gi = (int)(0xFFFFFFFFu - (unsigned)(pk & 0xFFFFFFFFull));
        winLDS = gi;
        if (sub == 0) selg[t] = gi;
      }
    }
    __syncthreads();
    const int gbi = winLDS;
    lx = pos[3 * gbi]; ly = pos[3 * gbi + 1]; lz = pos[3 * gbi + 2];  // bcast, L1/L2-hit
  }
}

// ---------- distributed kmeans kernel: 8 blocks/branch x 512 threads (round-11) ----------
__global__ __launch_bounds__(TPB) void branch_kernel(const float* __restrict__ logits,
                                                     const float* __restrict__ logits1,
                                                     const float* __restrict__ pfirst,
                                                     const float* __restrict__ psec,
                                                     const int* __restrict__ sel_base,
                                                     float* __restrict__ feaT_base,
                                                     float* __restrict__ accum,
                                                     float* __restrict__ apay,
                                                     unsigned* __restrict__ aflag,
                                                     float* __restrict__ cpay,
                                                     unsigned* __restrict__ cflag) {
  const int br = blockIdx.x >> 3, sub = blockIdx.x & 7;
  const float* fea_all = ((br < 2) ? logits : logits1) + (size_t)(br & 1) * N_PTS * CD;
  const float* pos     = ((br < 2) ? pfirst : psec) + (size_t)(br & 1) * N_PTS * 3;
  const int* selg = sel_base + (size_t)br * NS;
  float* feaT = feaT_base + (size_t)br * NS * CD;
  float*    Apay  = apay  + (size_t)br * NB_K * APAY_N;
  unsigned* Aflag = aflag + br * NB_K;
  float*    Cpay  = cpay  + (size_t)br * NB_K * 16;
  unsigned* Cflag = cflag + br * NB_K;
  const int base = sub * LPTS;

  __shared__ Sm sm;
  extern __shared__ char dynraw[];
  const int tid = threadIdx.x, w = tid >> 6, l = tid & 63;

  for (int i = tid; i < NS; i += TPB) sm.sel[i] = selg[i];
  __syncthreads();

  // ================= gather sampled pos into LDS (full 2048, redundant) =========
  float* pos_s = (float*)dynraw;             // [NS*3] 0..24576
  float* stag  = (float*)(dynraw + 24576);   // [64][257] transpose staging
  float* wbuf  = (float*)(dynraw + 24576);   // 40960 B, reused after transpose
  float* mdbuf = (float*)(dynraw + 98304);   // [NS] (position) / [LPTS] (feature)
  for (int i = tid; i < NS; i += TPB) {
    const int s = sm.sel[i];
    pos_s[3 * i] = pos[3 * s]; pos_s[3 * i + 1] = pos[3 * s + 1]; pos_s[3 * i + 2] = pos[3 * s + 2];
  }

  // ================= gather + transpose OWN feature slice -> feaT ===============
  for (int tile = base; tile < base + LPTS; tile += 64) {
    __syncthreads();
    for (int rr = w; rr < 64; rr += 8) {
      const int srow = sm.sel[tile + rr];
      const float4 v = *(const float4*)&fea_all[(size_t)srow * CD + 4 * l];
      float* dst = &stag[rr * 257 + 4 * l];
      dst[0] = v.x; dst[1] = v.y; dst[2] = v.z; dst[3] = v.w;
    }
    __syncthreads();
    for (int dd = 0; dd < 32; dd++) {
      const int dim = w * 32 + dd;
      feaT[(size_t)dim * NS + tile + l] = stag[l * 257 + dim];
    }
  }
  __syncthreads();

  // ================= initial centroids (greedy, positions; redundant) ===========
  if (tid == 0) { sm.c3[0][0] = pos_s[0]; sm.c3[0][1] = pos_s[1]; sm.c3[0][2] = pos_s[2]; }
  __syncthreads();
  for (int k = 1; k < KC; k++) {
    float lv = -1.f; int li = 0x7fffffff;
    #pragma unroll
    for (int r = 0; r < 4; r++) {
      const int i = 4 * tid + r;
      const float x = pos_s[3 * i], y = pos_s[3 * i + 1], z = pos_s[3 * i + 2];
      float a = 0.f;
      for (int j = 0; j < k; j++) {
        const float dx = x - sm.c3[j][0], dy = y - sm.c3[j][1], dz = z - sm.c3[j][2];
        a += dx * dx + dy * dy + dz * dz;
      }
      if (a > lv) { lv = a; li = i; }
    }
    float bv; int bi;
    block_argmax(lv, li, sm, bv, bi);
    if (tid == 0) { sm.c3[k][0] = pos_s[3 * bi]; sm.c3[k][1] = pos_s[3 * bi + 1]; sm.c3[k][2] = pos_s[3 * bi + 2]; }
    __syncthreads();
  }

  // ================= one kmeans step on positions (full 2048, redundant) ========
  {
    float a3[KC][3]; float cn[KC];
    #pragma unroll
    for (int k = 0; k < KC; k++) { a3[k][0] = 0.f; a3[k][1] = 0.f; a3[k][2] = 0.f; cn[k] = 0.f; }
    #pragma unroll
    for (int r = 0; r < 4; r++) {
      const int i = 4 * tid + r;
      const float x = pos_s[3 * i], y = pos_s[3 * i + 1], z = pos_s[3 * i + 2];
      float best = FLT_MAX; int bk = 0;
      #pragma unroll
      for (int k = 0; k < KC; k++) {
        const float dx = x - sm.c3[k][0], dy = y - sm.c3[k][1], dz = z - sm.c3[k][2];
        const float s = dx * dx + dy * dy + dz * dz;
        if (s < best) { best = s; bk = k; }
      }
      sm.idx[i] = bk;
      #pragma unroll
      for (int k = 0; k < KC; k++) {
        const float m = (bk == k) ? 1.f : 0.f;
        a3[k][0] += m * x; a3[k][1] += m * y; a3[k][2] += m * z; cn[k] += m;
      }
    }
    reduce_counts(sm, cn);
    #pragma unroll
    for (int k = 0; k < KC; k++) {
      #pragma unroll
      for (int c = 0; c < 3; c++) {
        float s = a3[k][c];
        #pragma unroll
        for (int off = 32; off; off >>= 1) s += __shfl_xor(s, off);
        a3[k][c] = s;
      }
    }
    __syncthreads();
    if (l == 0) {
      #pragma unroll
      for (int k = 0; k < KC; k++) {
        wbuf[w * 16 + k * 3 + 0] = a3[k][0];
        wbuf[w * 16 + k * 3 + 1] = a3[k][1];
        wbuf[w * 16 + k * 3 + 2] = a3[k][2];
      }
    }
    __syncthreads();
    if (tid == 0) {
      for (int k = 0; k < KC; k++)
        for (int c = 0; c < 3; c++) {
          float s = 0.f;
          for (int g = 0; g < 8; g++) s += wbuf[g * 16 + k * 3 + c];
          sm.c3[k][c] = s / fmaxf(sm.cnt[k], 1.f);
        }
    }
    __syncthreads();
  }
  float psum = 0.f;
  #pragma unroll
  for (int r = 0; r < 4; r++) {
    const int i = 4 * tid + r; const int k = sm.idx[i];
    const float dx = pos_s[3 * i] - sm.c3[k][0];
    const float dy = pos_s[3 * i + 1] - sm.c3[k][1];
    const float dz = pos_s[3 * i + 2] - sm.c3[k][2];
    psum += dx * dx + dy * dy + dz * dz;
  }
  const float sse_n = sqrtf(block_sum(psum, sm));
  {  // empty-cluster fixup (positions, full 2048, redundant)
    int nmask = 0;
    #pragma unroll
    for (int k = 0; k < KC; k++) nmask |= (sm.cnt[k] == 0.f) ? (1 << k) : 0;
    if (nmask) {
      #pragma unroll
      for (int r = 0; r < 4; r++) {
        const int i = 4 * tid + r;
        const float x = pos_s[3 * i], y = pos_s[3 * i + 1], z = pos_s[3 * i + 2];
        float s = 0.f;
        for (int k = 0; k < KC; k++) {
          if (sm.cnt[k] > 0.f) {
            const float dx = x - sm.c3[k][0], dy = y - sm.c3[k][1], dz = z - sm.c3[k][2];
            s += sqrtf(dx * dx + dy * dy + dz * dz + 1e-12f);
          }
        }
        mdbuf[i] = s;
      }
      __syncthreads();
      top5(sm, mdbuf);
      if (tid == 0) {
        int cum = 0;
        for (int k = 0; k < KC; k++) {
          if (sm.cnt[k] == 0.f) {
            const int rk = (cum < KC) ? cum : (KC - 1);
            const int src = sm.far5[rk];
            sm.c3[k][0] = pos_s[3 * src]; sm.c3[k][1] = pos_s[3 * src + 1]; sm.c3[k][2] = pos_s[3 * src + 2];
            cum++;
          }
        }
      }
      __syncthreads();
    }
  }

  // ================= distributed kmeans on features =================
  assign3_local(sm, feaT, base);
  float sse_fin = iter_core(sm, wbuf, mdbuf, fea_all, feaT,
                            Apay, Aflag, Cpay, Cflag, base, sub, 1u);
  float sse_pre = sse_fin;
  bool done = fabsf(sse_fin) < TOLV;
  for (int it = 1; it < MAX_IT && !done; it++) {
    assign_full_local(sm, feaT, base);
    const float s2 = iter_core(sm, wbuf, mdbuf, fea_all, feaT,
                               Apay, Aflag, Cpay, Cflag, base, sub, (unsigned)(it + 1));
    sse_fin = s2;
    done = fabsf(s2 - sse_pre) < TOLV;
    sse_pre = s2;
  }
  if (sub == 0 && tid == 0) atomicAdd(&accum[1], sse_n + sse_fin);
}

// ---------- global point loss (cosine similarity) ----------
__global__ __launch_bounds__(256) void gp_kernel(const float* __restrict__ A,
                                                 const float* __restrict__ B,
                                                 float* __restrict__ accum) {
  __shared__ float bacc;
  const int tid = threadIdx.x, l = tid & 63, w = tid >> 6;
  if (tid == 0) bacc = 0.f;
  __syncthreads();
  const int gw = blockIdx.x * 4 + w;
  const int NW = gridDim.x * 4;
  float lsum = 0.f;
  for (int p = gw; p < 65536; p += NW) {
    const float4 a = *(const float4*)&A[(size_t)p * CD + 4 * l];
    const float4 b = *(const float4*)&B[(size_t)p * CD + 4 * l];
    float ab = a.x * b.x + a.y * b.y + a.z * b.z + a.w * b.w;
    float aa = a.x * a.x + a.y * a.y + a.z * a.z + a.w * a.w;
    float bb = b.x * b.x + b.y * b.y + b.z * b.z + b.w * b.w;
    #pragma unroll
    for (int off = 32; off; off >>= 1) {
      ab += __shfl_xor(ab, off); aa += __shfl_xor(aa, off); bb += __shfl_xor(bb, off);
    }
    if (l == 0) lsum += ab / fmaxf(sqrtf(aa) * sqrtf(bb), 1e-8f);
  }
  if (l == 0) atomicAdd(&bacc, lsum);
  __syncthreads();
  if (tid == 0) atomicAdd(&accum[0], bacc);
}

__global__ void fin_kernel(const float* __restrict__ accum, float* __restrict__ out) {
  out[0] = -accum[0] / 65536.0f + accum[1];
}

extern "C" void kernel_launch(void* const* d_in, const int* in_sizes, int n_in,
                              void* d_out, int out_size, void* d_ws, size_t ws_size,
                              hipStream_t stream) {
  const float* logits  = (const float*)d_in[0];
  const float* logits1 = (const float*)d_in[1];
  const float* pfirst  = (const float*)d_in[2];
  const float* psec    = (const float*)d_in[3];
  float* out = (float*)d_out;
  float* wsf = (float*)d_ws;
  // workspace layout (float offsets):
  float* accum = wsf;                                          // [0..16)
  int* selg = (int*)(wsf + 16);                                // 4*NS ints        @16
  unsigned long long* cand = (unsigned long long*)(wsf + 16 + 4 * NS);  // @8208 (byte%8==0)
  unsigned* aflag = (unsigned*)(wsf + 139280);                 // after cand (131072 floats)
  unsigned* cflag = (unsigned*)(wsf + 139312);
  float* apay = wsf + 139344;                                  // 4*8*1285 = 41120 floats
  float* cpay = wsf + 180464;                                  // 4*8*16 = 512 floats
  float* feaT = wsf + 180976;                                  // 4 branches x [CD][NS] = 8 MB

  static std::once_flag once;
  std::call_once(once, []() {
    (void)hipFuncSetAttribute((const void*)branch_kernel,
                              hipFuncAttributeMaxDynamicSharedMemorySize, DYN_K);
    (void)hipGetLastError();
  });

  // zero accum + selg + cand + flags (fresh cand slots + flag seqs start at 0 -> poll ==n
  // with n>=1 is ABA-free; payload regions need no zeroing, guarded by flags)
  (void)hipMemsetAsync(wsf, 0, (size_t)139344 * 4, stream);
  gp_kernel<<<1024, 256, 0, stream>>>(logits, logits1, accum);
  fps_kernel<<<64, TPB_F, 0, stream>>>(pfirst, psec, selg, cand);   // 32 active + 32 dead
  branch_kernel<<<4 * NB_K, TPB, DYN_K, stream>>>(logits, logits1, pfirst, psec,
                                                  selg, feaT, accum,
                                                  apay, aflag, cpay, cflag);
  fin_kernel<<<1, 1, 0, stream>>>(accum, out);
}

// Round 16
// 5782.381 us; speedup vs baseline: 1.1106x; 1.0902x over previous
//
#include <hip/hip_runtime.h>
#include <math.h>
#include <float.h>
#include <mutex>

// Problem constants (match reference)
#define N_PTS  32768
#define NS     2048      // N_PTS/16 downsample
#define CD     256
#define KC     5
#define TPB    512       // kmeans kernel threads/block
#define TPB_F  512       // FPS kernel threads/block
#define NB_F   8         // FPS blocks per branch
#define NB_K   8         // kmeans blocks per branch (distributed kmeans)
#define LPTS   256       // NS/NB_K local sampled points per kmeans block
#define APAY_N 1285      // A-payload floats: counts[5] + sums[5*256]
#define MAX_IT 100
#define TOLV   1e-3f
#define DYN_K  131072    // kmeans dyn LDS: pos_s(24576) + stag/wbuf + mdbuf(@98304)

struct Sm {
  int   sel[NS];        // FPS-selected indices into the 32768 points (full copy)
  int   idx[NS];        // cluster assignment (position phase: 2048; feature phase: local 256)
  float cm[KC][CD];     // feature-space centroids (globally reduced, identical per block)
  float cc2h[KC];       // 0.5*|c|^2
  float c3[KC][3];      // position-space centroids
  float cnt[KC];        // counts (position phase: global; feature phase: LOCAL partials)
  float wc[8][KC];      // per-wave count partials
  float redf[8];
  int   redi[8];
  int   far5[KC];
};

// ---------- block reductions (512 threads = 8 waves) ----------
__device__ __forceinline__ void block_argmax(float v, int i, Sm& sm, float& bv, int& bi) {
  #pragma unroll
  for (int off = 32; off; off >>= 1) {
    float v2 = __shfl_xor(v, off);
    int   i2 = __shfl_xor(i, off);
    if (v2 > v || (v2 == v && i2 < i)) { v = v2; i = i2; }
  }
  __syncthreads();
  if ((threadIdx.x & 63) == 0) { sm.redf[threadIdx.x >> 6] = v; sm.redi[threadIdx.x >> 6] = i; }
  __syncthreads();
  bv = sm.redf[0]; bi = sm.redi[0];
  #pragma unroll
  for (int g = 1; g < 8; g++) {
    float v2 = sm.redf[g]; int i2 = sm.redi[g];
    if (v2 > bv || (v2 == bv && i2 < bi)) { bv = v2; bi = i2; }
  }
}

__device__ __forceinline__ float block_sum(float v, Sm& sm) {
  #pragma unroll
  for (int off = 32; off; off >>= 1) v += __shfl_xor(v, off);
  __syncthreads();
  if ((threadIdx.x & 63) == 0) sm.redf[threadIdx.x >> 6] = v;
  __syncthreads();
  float s = 0.f;
  #pragma unroll
  for (int g = 0; g < 8; g++) s += sm.redf[g];
  return s;  // identical in all threads
}

__device__ __forceinline__ void reduce_counts(Sm& sm, float cn[KC]) {
  const int w = threadIdx.x >> 6, l = threadIdx.x & 63;
  #pragma unroll
  for (int k = 0; k < KC; k++) {
    float s = cn[k];
    #pragma unroll
    for (int off = 32; off; off >>= 1) s += __shfl_xor(s, off);
    cn[k] = s;
  }
  __syncthreads();
  if (l == 0) {
    #pragma unroll
    for (int k = 0; k < KC; k++) sm.wc[w][k] = cn[k];
  }
  __syncthreads();
  if (threadIdx.x == 0) {
    #pragma unroll
    for (int k = 0; k < KC; k++) {
      float s = 0.f;
      #pragma unroll
      for (int g = 0; g < 8; g++) s += sm.wc[g][k];
      sm.cnt[k] = s;
    }
  }
  __syncthreads();
}

__device__ void top5(Sm& sm, float* mdbuf) {   // position-phase (2048-wide) top5
  for (int r5 = 0; r5 < KC; r5++) {
    float lv = -1.f; int li = 0x7fffffff;
    #pragma unroll
    for (int r = 0; r < 4; r++) {
      const int i = 4 * threadIdx.x + r;
      const float v = mdbuf[i];
      if (v > lv) { lv = v; li = i; }
    }
    float bv; int bi;
    block_argmax(lv, li, sm, bv, bi);
    if (threadIdx.x == 0) { sm.far5[r5] = bi; mdbuf[bi] = -2.f; }
    __syncthreads();
  }
}

// ---------- distributed kmeans: local assignment over LPTS points ----------
__device__ void assign3_local(Sm& sm, const float* feaT, int base) {
  const int tid = threadIdx.x;
  float cn[KC] = {0.f, 0.f, 0.f, 0.f, 0.f};
  if (tid < LPTS) {
    const float x0 = feaT[0 * NS + base + tid];
    const float x1 = feaT[1 * NS + base + tid];
    const float x2 = feaT[2 * NS + base + tid];
    float best = FLT_MAX; int bk = 0;
    #pragma unroll
    for (int k = 0; k < KC; k++) {
      const float d0 = x0 - sm.c3[k][0];
      const float d1 = x1 - sm.c3[k][1];
      const float d2 = x2 - sm.c3[k][2];
      const float s = d0 * d0 + d1 * d1 + d2 * d2;
      if (s < best) { best = s; bk = k; }
    }
    sm.idx[tid] = bk;
    cn[bk] = 1.f;
  }
  reduce_counts(sm, cn);   // sm.cnt = LOCAL counts (published in A)
}

__device__ void assign_full_local(Sm& sm, const float* feaT, int base) {
  const int tid = threadIdx.x;
  float cn[KC] = {0.f, 0.f, 0.f, 0.f, 0.f};
  if (tid < LPTS) {
    float dot[KC] = {0.f, 0.f, 0.f, 0.f, 0.f};
    for (int j = 0; j < CD; j++) {
      const float x = feaT[(size_t)j * NS + base + tid];
      #pragma unroll
      for (int k = 0; k < KC; k++) dot[k] += x * sm.cm[k][j];
    }
    float best = dot[0] - sm.cc2h[0]; int bk = 0;
    #pragma unroll
    for (int k = 1; k < KC; k++) {
      const float s = dot[k] - sm.cc2h[k];
      if (s > best) { best = s; bk = k; }
    }
    sm.idx[tid] = bk;
    cn[bk] = 1.f;
  }
  reduce_counts(sm, cn);
}

// ---------- distributed kmeans iteration core (round-11-verified) ----------
__device__ float iter_core(Sm& sm, float* wbuf, float* mdbuf,
                           const float* fea_all, const float* feaT,
                           float* Apay, unsigned* Aflag, float* Cpay, unsigned* Cflag,
                           int base, int sub, unsigned n) {
  const int tid = threadIdx.x, w = tid >> 6, l = tid & 63;
  float4 acc[KC];
  #pragma unroll
  for (int k = 0; k < KC; k++) acc[k] = make_float4(0.f, 0.f, 0.f, 0.f);
  #pragma unroll 4
  for (int ii = 0; ii < 32; ii++) {
    const int li = (w << 5) + ii;
    const int k = __builtin_amdgcn_readfirstlane(sm.idx[li]);
    const float4 v = *(const float4*)&fea_all[(size_t)sm.sel[base + li] * CD + 4 * l];
    switch (k) {
      case 0: acc[0].x += v.x; acc[0].y += v.y; acc[0].z += v.z; acc[0].w += v.w; break;
      case 1: acc[1].x += v.x; acc[1].y += v.y; acc[1].z += v.z; acc[1].w += v.w; break;
      case 2: acc[2].x += v.x; acc[2].y += v.y; acc[2].z += v.z; acc[2].w += v.w; break;
      case 3: acc[3].x += v.x; acc[3].y += v.y; acc[3].z += v.z; acc[3].w += v.w; break;
      default: acc[4].x += v.x; acc[4].y += v.y; acc[4].z += v.z; acc[4].w += v.w; break;
    }
  }
  #pragma unroll
  for (int k = 0; k < KC; k++) *(float4*)&wbuf[(w * KC + k) * CD + 4 * l] = acc[k];
  __syncthreads();
  // publish A = {local counts[5], local sums[1280]}
  float* myA = Apay + sub * APAY_N;
  for (int e = tid; e < APAY_N; e += TPB) {
    float s;
    if (e < KC) s = sm.cnt[e];
    else {
      s = 0.f;
      #pragma unroll
      for (int g = 0; g < 8; g++) s += wbuf[g * (KC * CD) + (e - KC)];
    }
    myA[e] = s;
  }
  __threadfence();
  __syncthreads();
  if (tid == 0) __hip_atomic_store(&Aflag[sub], n, __ATOMIC_RELEASE, __HIP_MEMORY_SCOPE_AGENT);
  if (w == 0 && l < NB_K) {
    while (__hip_atomic_load(&Aflag[l], __ATOMIC_ACQUIRE, __HIP_MEMORY_SCOPE_AGENT) != n)
      __builtin_amdgcn_s_sleep(1);
  }
  __syncthreads();
  // reduce A (redundant, identical everywhere); b ascending = points ascending
  float cntk[KC];
  #pragma unroll
  for (int k = 0; k < KC; k++) {
    float s = 0.f;
    for (int b = 0; b < NB_K; b++) s += Apay[b * APAY_N + k];
    cntk[k] = s;
  }
  for (int e = tid; e < KC * CD; e += TPB) {
    float s = 0.f;
    for (int b = 0; b < NB_K; b++) s += Apay[b * APAY_N + KC + e];
    (&sm.cm[0][0])[e] = s / fmaxf(cntk[e >> 8], 1.f);
  }
  __syncthreads();
  // local sse partial over first 3 feature dims (pre-fixup cm)
  float contrib = 0.f;
  if (tid < LPTS) {
    const float x0 = feaT[0 * NS + base + tid];
    const float x1 = feaT[1 * NS + base + tid];
    const float x2 = feaT[2 * NS + base + tid];
    const int k = sm.idx[tid];
    const float d0 = x0 - sm.cm[k][0], d1 = x1 - sm.cm[k][1], d2 = x2 - sm.cm[k][2];
    contrib = d0 * d0 + d1 * d1 + d2 * d2;
  }
  const float lps = block_sum(contrib, sm);
  // empty-cluster metric + local top5 (rare; nmask identical across blocks)
  int nmask = 0;
  #pragma unroll
  for (int k = 0; k < KC; k++) nmask |= (cntk[k] == 0.f) ? (1 << k) : 0;
  float f5v[KC] = {0.f, 0.f, 0.f, 0.f, 0.f};
  int   f5i[KC] = {0, 0, 0, 0, 0};
  if (nmask) {
    if (tid < LPTS) {
      float dd[KC] = {0.f, 0.f, 0.f, 0.f, 0.f};
      for (int j = 0; j < CD; j++) {
        const float x = feaT[(size_t)j * NS + base + tid];
        #pragma unroll
        for (int k = 0; k < KC; k++) { const float d = x - sm.cm[k][j]; dd[k] += d * d; }
      }
      float s = 0.f;
      #pragma unroll
      for (int k = 0; k < KC; k++)
        if (cntk[k] > 0.f) s += sqrtf(fmaxf(dd[k], 0.f) + 1e-12f);
      mdbuf[tid] = s;
    }
    __syncthreads();
    for (int r5 = 0; r5 < KC; r5++) {
      const float lv = (tid < LPTS) ? mdbuf[tid] : -1.f;
      const int   li = (tid < LPTS) ? (base + tid) : 0x7fffffff;
      float bv; int bi;
      block_argmax(lv, li, sm, bv, bi);
      f5v[r5] = bv; f5i[r5] = bi;           // identical in all threads
      if (tid < LPTS && base + tid == bi) mdbuf[tid] = -2.f;
      __syncthreads();
    }
  }
  // publish C = {psum, top5 values, top5 global indices (bitcast)}
  float* myC = Cpay + sub * 16;
  if (tid == 0) {
    myC[0] = lps;
    #pragma unroll
    for (int r = 0; r < KC; r++) { myC[1 + r] = f5v[r]; myC[6 + r] = __int_as_float(f5i[r]); }
  }
  __threadfence();
  __syncthreads();
  if (tid == 0) __hip_atomic_store(&Cflag[sub], n, __ATOMIC_RELEASE, __HIP_MEMORY_SCOPE_AGENT);
  if (w == 0 && l < NB_K) {
    while (__hip_atomic_load(&Cflag[l], __ATOMIC_ACQUIRE, __HIP_MEMORY_SCOPE_AGENT) != n)
      __builtin_amdgcn_s_sleep(1);
  }
  __syncthreads();
  // read C: sse; merged exact top5 (value desc, index asc == lax.top_k) + fixup
  float ps = 0.f;
  for (int b = 0; b < NB_K; b++) ps += Cpay[b * 16];
  const float sse = sqrtf(ps);
  if (nmask) {
    unsigned long long used = 0ull;
    int farg[KC];
    for (int r5 = 0; r5 < KC; r5++) {
      float bv = -3.f; int bi = 0x7fffffff; int bs = 0;
      for (int s = 0; s < NB_K * KC; s++) {
        if (used & (1ull << s)) continue;
        const float v = Cpay[(s / KC) * 16 + 1 + (s % KC)];
        const int   i = __float_as_int(Cpay[(s / KC) * 16 + 6 + (s % KC)]);
        if (v > bv || (v == bv && i < bi)) { bv = v; bi = i; bs = s; }
      }
      used |= (1ull << bs);
      farg[r5] = bi;
    }
    int cum = 0;
    for (int k = 0; k < KC; k++) {     // uniform across threads and blocks
      if (cntk[k] == 0.f) {
        const int rk = (cum < KC) ? cum : (KC - 1);
        const int row = sm.sel[farg[rk]];
        for (int d = tid; d < CD; d += TPB) sm.cm[k][d] = fea_all[(size_t)row * CD + d];
        cum++;
      }
    }
    __syncthreads();
  }
  // cc2h (after fixup, for next assignment)
  if (tid < KC * 64) {
    const float4 c = *(const float4*)&sm.cm[w][4 * l];
    float s = c.x * c.x + c.y * c.y + c.z * c.z + c.w * c.w;
    #pragma unroll
    for (int off = 32; off; off >>= 1) s += __shfl_xor(s, off);
    if (l == 0) sm.cc2h[w] = 0.5f * s;
  }
  __syncthreads();
  return sse;
}

// ---------- FPS kernel: round-12 verified optimum (4743 us) ----------
// 8 blocks/branch x 512 threads; XCD grouping br=blockIdx&3; [t][sub] cand layout
// (shared line is read-efficient, round-13); winner-lane LDS publish + wave-0
// shuffle reduce; wave-0-only poll (round-8 lesson); LDS broadcast + read-only
// pos[3*gbi] winner load (round-9 lesson). Sync floor ~2.3us/iter is structural:
// contention (r13), agent-count (r14), and XCD-locality (r15) attacks all failed.
// Packing: u64 = bit63|fbits<<32|(0xFFFFFFFF-idx); u64-max == (max value, min
// index) == jnp.argmax first-occurrence. Fresh per-t slots (memset per launch).
__global__ __launch_bounds__(TPB_F) void fps_kernel(const float* __restrict__ pfirst,
                                                    const float* __restrict__ psec,
                                                    int* __restrict__ sel_base,
                                                    unsigned long long* __restrict__ cand) {
  const int br = blockIdx.x & 3, sub = blockIdx.x >> 2;   // XCD-grouped mapping
  const float* pos = ((br < 2) ? pfirst : psec) + (size_t)(br & 1) * N_PTS * 3;
  int* selg = sel_base + (size_t)br * NS;
  unsigned long long* mycand = cand + (size_t)br * NS * NB_F;  // [t][sub] within branch
  __shared__ float redf[8];
  __shared__ int   redi[8];
  __shared__ int   winLDS;
  const int tid = threadIdx.x, w = tid >> 6, l = tid & 63;
  const int base = sub * 4096;

  float px[8], py[8], pz[8], dd[8];          // 32 registers, static indices only
  #pragma unroll
  for (int k = 0; k < 8; k++) {
    const int p = base + tid + k * TPB_F;
    px[k] = pos[3 * p]; py[k] = pos[3 * p + 1]; pz[k] = pos[3 * p + 2];
    dd[k] = 1e10f;
  }
  if (sub == 0 && tid == 0) selg[0] = 0;
  float lx = pos[0], ly = pos[1], lz = pos[2];

  for (int t = 1; t < NS; t++) {
    float bv = -1.f; int bi = 0x7fffffff;
    #pragma unroll
    for (int k = 0; k < 8; k++) {
      const float dx = px[k] - lx, dy = py[k] - ly, dz = pz[k] - lz;
      const float dist = dx * dx + dy * dy + dz * dz;
      dd[k] = fminf(dd[k], dist);
      if (dd[k] > bv) { bv = dd[k]; bi = base + tid + k * TPB_F; }
    }
    const int myi = bi;
    // wave-level (value desc, index asc) argmax
    #pragma unroll
    for (int off = 32; off; off >>= 1) {
      const float v2 = __shfl_xor(bv, off);
      const int   i2 = __shfl_xor(bi, off);
      if (v2 > bv || (v2 == bv && i2 < bi)) { bv = v2; bi = i2; }
    }
    // unique wave-winner lane publishes to LDS (per-lane indices disjoint)
    if (myi == bi) { redf[w] = bv; redi[w] = bi; }
    __syncthreads();
    // wave 0 only: shuffle block-reduce -> publish -> poll -> LDS broadcast
    if (w == 0) {
      float cv = -1.f; int ci = 0x7fffffff;
      if (l < 8) { cv = redf[l]; ci = redi[l]; }
      #pragma unroll
      for (int off = 4; off; off >>= 1) {
        const float v2 = __shfl_xor(cv, off);
        const int   i2 = __shfl_xor(ci, off);
        if (v2 > cv || (v2 == cv && i2 < ci)) { cv = v2; ci = i2; }
      }
      if (l == 0) {
        const unsigned long long pk = (1ULL << 63)
            | ((unsigned long long)__float_as_uint(cv) << 32)
            | (unsigned long long)(0xFFFFFFFFu - (unsigned)ci);
        __hip_atomic_store(&mycand[(size_t)t * NB_F + sub], pk,
                           __ATOMIC_RELEASE, __HIP_MEMORY_SCOPE_AGENT);
      }
      unsigned long long pk = 0ULL;
      if (l < NB_F) {
        pk = __hip_atomic_load(&mycand[(size_t)t * NB_F + l],
                               __ATOMIC_ACQUIRE, __HIP_MEMORY_SCOPE_AGENT);
        while (pk == 0ULL) {
          __builtin_amdgcn_s_sleep(1);
          pk = __hip_atomic_load(&mycand[(size_t)t * NB_F + l],
                                 __ATOMIC_ACQUIRE, __HIP_MEMORY_SCOPE_AGENT);
        }
      }
      #pragma unroll
      for (int off = 4; off; off >>= 1) {
        const unsigned long long o = __shfl_xor(pk, off, NB_F);
        pk = (o > pk) ? o : pk;
      }
      if (l == 0) {
        const int gi = (int)(0xFFFFFFFFu - (unsigned)(pk & 0xFFFFFFFFull));
        winLDS = gi;
        if (sub == 0) selg[t] = gi;
      }
    }
    __syncthreads();
    const int gbi = winLDS;
    lx = pos[3 * gbi]; ly = pos[3 * gbi + 1]; lz = pos[3 * gbi + 2];  // bcast, L1/L2-hit
  }
}

// ---------- distributed kmeans kernel: 8 blocks/branch x 512 threads (round-11) ----------
__global__ __launch_bounds__(TPB) void branch_kernel(const float* __restrict__ logits,
                                                     const float* __restrict__ logits1,
                                                     const float* __restrict__ pfirst,
                                                     const float* __restrict__ psec,
                                                     const int* __restrict__ sel_base,
                                                     float* __restrict__ feaT_base,
                                                     float* __restrict__ accum,
                                                     float* __restrict__ apay,
                                                     unsigned* __restrict__ aflag,
                                                     float* __restrict__ cpay,
                                                     unsigned* __restrict__ cflag) {
  const int br = blockIdx.x >> 3, sub = blockIdx.x & 7;
  const float* fea_all = ((br < 2) ? logits : logits1) + (size_t)(br & 1) * N_PTS * CD;
  const float* pos     = ((br < 2) ? pfirst : psec) + (size_t)(br & 1) * N_PTS * 3;
  const int* selg = sel_base + (size_t)br * NS;
  float* feaT = feaT_base + (size_t)br * NS * CD;
  float*    Apay  = apay  + (size_t)br * NB_K * APAY_N;
  unsigned* Aflag = aflag + br * NB_K;
  float*    Cpay  = cpay  + (size_t)br * NB_K * 16;
  unsigned* Cflag = cflag + br * NB_K;
  const int base = sub * LPTS;

  __shared__ Sm sm;
  extern __shared__ char dynraw[];
  const int tid = threadIdx.x, w = tid >> 6, l = tid & 63;

  for (int i = tid; i < NS; i += TPB) sm.sel[i] = selg[i];
  __syncthreads();

  // ================= gather sampled pos into LDS (full 2048, redundant) =========
  float* pos_s = (float*)dynraw;             // [NS*3] 0..24576
  float* stag  = (float*)(dynraw + 24576);   // [64][257] transpose staging
  float* wbuf  = (float*)(dynraw + 24576);   // 40960 B, reused after transpose
  float* mdbuf = (float*)(dynraw + 98304);   // [NS] (position) / [LPTS] (feature)
  for (int i = tid; i < NS; i += TPB) {
    const int s = sm.sel[i];
    pos_s[3 * i] = pos[3 * s]; pos_s[3 * i + 1] = pos[3 * s + 1]; pos_s[3 * i + 2] = pos[3 * s + 2];
  }

  // ================= gather + transpose OWN feature slice -> feaT ===============
  for (int tile = base; tile < base + LPTS; tile += 64) {
    __syncthreads();
    for (int rr = w; rr < 64; rr += 8) {
      const int srow = sm.sel[tile + rr];
      const float4 v = *(const float4*)&fea_all[(size_t)srow * CD + 4 * l];
      float* dst = &stag[rr * 257 + 4 * l];
      dst[0] = v.x; dst[1] = v.y; dst[2] = v.z; dst[3] = v.w;
    }
    __syncthreads();
    for (int dd = 0; dd < 32; dd++) {
      const int dim = w * 32 + dd;
      feaT[(size_t)dim * NS + tile + l] = stag[l * 257 + dim];
    }
  }
  __syncthreads();

  // ================= initial centroids (greedy, positions; redundant) ===========
  if (tid == 0) { sm.c3[0][0] = pos_s[0]; sm.c3[0][1] = pos_s[1]; sm.c3[0][2] = pos_s[2]; }
  __syncthreads();
  for (int k = 1; k < KC; k++) {
    float lv = -1.f; int li = 0x7fffffff;
    #pragma unroll
    for (int r = 0; r < 4; r++) {
      const int i = 4 * tid + r;
      const float x = pos_s[3 * i], y = pos_s[3 * i + 1], z = pos_s[3 * i + 2];
      float a = 0.f;
      for (int j = 0; j < k; j++) {
        const float dx = x - sm.c3[j][0], dy = y - sm.c3[j][1], dz = z - sm.c3[j][2];
        a += dx * dx + dy * dy + dz * dz;
      }
      if (a > lv) { lv = a; li = i; }
    }
    float bv; int bi;
    block_argmax(lv, li, sm, bv, bi);
    if (tid == 0) { sm.c3[k][0] = pos_s[3 * bi]; sm.c3[k][1] = pos_s[3 * bi + 1]; sm.c3[k][2] = pos_s[3 * bi + 2]; }
    __syncthreads();
  }

  // ================= one kmeans step on positions (full 2048, redundant) ========
  {
    float a3[KC][3]; float cn[KC];
    #pragma unroll
    for (int k = 0; k < KC; k++) { a3[k][0] = 0.f; a3[k][1] = 0.f; a3[k][2] = 0.f; cn[k] = 0.f; }
    #pragma unroll
    for (int r = 0; r < 4; r++) {
      const int i = 4 * tid + r;
      const float x = pos_s[3 * i], y = pos_s[3 * i + 1], z = pos_s[3 * i + 2];
      float best = FLT_MAX; int bk = 0;
      #pragma unroll
      for (int k = 0; k < KC; k++) {
        const float dx = x - sm.c3[k][0], dy = y - sm.c3[k][1], dz = z - sm.c3[k][2];
        const float s = dx * dx + dy * dy + dz * dz;
        if (s < best) { best = s; bk = k; }
      }
      sm.idx[i] = bk;
      #pragma unroll
      for (int k = 0; k < KC; k++) {
        const float m = (bk == k) ? 1.f : 0.f;
        a3[k][0] += m * x; a3[k][1] += m * y; a3[k][2] += m * z; cn[k] += m;
      }
    }
    reduce_counts(sm, cn);
    #pragma unroll
    for (int k = 0; k < KC; k++) {
      #pragma unroll
      for (int c = 0; c < 3; c++) {
        float s = a3[k][c];
        #pragma unroll
        for (int off = 32; off; off >>= 1) s += __shfl_xor(s, off);
        a3[k][c] = s;
      }
    }
    __syncthreads();
    if (l == 0) {
      #pragma unroll
      for (int k = 0; k < KC; k++) {
        wbuf[w * 16 + k * 3 + 0] = a3[k][0];
        wbuf[w * 16 + k * 3 + 1] = a3[k][1];
        wbuf[w * 16 + k * 3 + 2] = a3[k][2];
      }
    }
    __syncthreads();
    if (tid == 0) {
      for (int k = 0; k < KC; k++)
        for (int c = 0; c < 3; c++) {
          float s = 0.f;
          for (int g = 0; g < 8; g++) s += wbuf[g * 16 + k * 3 + c];
          sm.c3[k][c] = s / fmaxf(sm.cnt[k], 1.f);
        }
    }
    __syncthreads();
  }
  float psum = 0.f;
  #pragma unroll
  for (int r = 0; r < 4; r++) {
    const int i = 4 * tid + r; const int k = sm.idx[i];
    const float dx = pos_s[3 * i] - sm.c3[k][0];
    const float dy = pos_s[3 * i + 1] - sm.c3[k][1];
    const float dz = pos_s[3 * i + 2] - sm.c3[k][2];
    psum += dx * dx + dy * dy + dz * dz;
  }
  const float sse_n = sqrtf(block_sum(psum, sm));
  {  // empty-cluster fixup (positions, full 2048, redundant)
    int nmask = 0;
    #pragma unroll
    for (int k = 0; k < KC; k++) nmask |= (sm.cnt[k] == 0.f) ? (1 << k) : 0;
    if (nmask) {
      #pragma unroll
      for (int r = 0; r < 4; r++) {
        const int i = 4 * tid + r;
        const float x = pos_s[3 * i], y = pos_s[3 * i + 1], z = pos_s[3 * i + 2];
        float s = 0.f;
        for (int k = 0; k < KC; k++) {
          if (sm.cnt[k] > 0.f) {
            const float dx = x - sm.c3[k][0], dy = y - sm.c3[k][1], dz = z - sm.c3[k][2];
            s += sqrtf(dx * dx + dy * dy + dz * dz + 1e-12f);
          }
        }
        mdbuf[i] = s;
      }
      __syncthreads();
      top5(sm, mdbuf);
      if (tid == 0) {
        int cum = 0;
        for (int k = 0; k < KC; k++) {
          if (sm.cnt[k] == 0.f) {
            const int rk = (cum < KC) ? cum : (KC - 1);
            const int src = sm.far5[rk];
            sm.c3[k][0] = pos_s[3 * src]; sm.c3[k][1] = pos_s[3 * src + 1]; sm.c3[k][2] = pos_s[3 * src + 2];
            cum++;
          }
        }
      }
      __syncthreads();
    }
  }

  // ================= distributed kmeans on features =================
  assign3_local(sm, feaT, base);
  float sse_fin = iter_core(sm, wbuf, mdbuf, fea_all, feaT,
                            Apay, Aflag, Cpay, Cflag, base, sub, 1u);
  float sse_pre = sse_fin;
  bool done = fabsf(sse_fin) < TOLV;
  for (int it = 1; it < MAX_IT && !done; it++) {
    assign_full_local(sm, feaT, base);
    const float s2 = iter_core(sm, wbuf, mdbuf, fea_all, feaT,
                               Apay, Aflag, Cpay, Cflag, base, sub, (unsigned)(it + 1));
    sse_fin = s2;
    done = fabsf(s2 - sse_pre) < TOLV;
    sse_pre = s2;
  }
  if (sub == 0 && tid == 0) atomicAdd(&accum[1], sse_n + sse_fin);
}

// ---------- global point loss (cosine similarity) ----------
__global__ __launch_bounds__(256) void gp_kernel(const float* __restrict__ A,
                                                 const float* __restrict__ B,
                                                 float* __restrict__ accum) {
  __shared__ float bacc;
  const int tid = threadIdx.x, l = tid & 63, w = tid >> 6;
  if (tid == 0) bacc = 0.f;
  __syncthreads();
  const int gw = blockIdx.x * 4 + w;
  const int NW = gridDim.x * 4;
  float lsum = 0.f;
  for (int p = gw; p < 65536; p += NW) {
    const float4 a = *(const float4*)&A[(size_t)p * CD + 4 * l];
    const float4 b = *(const float4*)&B[(size_t)p * CD + 4 * l];
    float ab = a.x * b.x + a.y * b.y + a.z * b.z + a.w * b.w;
    float aa = a.x * a.x + a.y * a.y + a.z * a.z + a.w * a.w;
    float bb = b.x * b.x + b.y * b.y + b.z * b.z + b.w * b.w;
    #pragma unroll
    for (int off = 32; off; off >>= 1) {
      ab += __shfl_xor(ab, off); aa += __shfl_xor(aa, off); bb += __shfl_xor(bb, off);
    }
    if (l == 0) lsum += ab / fmaxf(sqrtf(aa) * sqrtf(bb), 1e-8f);
  }
  if (l == 0) atomicAdd(&bacc, lsum);
  __syncthreads();
  if (tid == 0) atomicAdd(&accum[0], bacc);
}

__global__ void fin_kernel(const float* __restrict__ accum, float* __restrict__ out) {
  out[0] = -accum[0] / 65536.0f + accum[1];
}

extern "C" void kernel_launch(void* const* d_in, const int* in_sizes, int n_in,
                              void* d_out, int out_size, void* d_ws, size_t ws_size,
                              hipStream_t stream) {
  const float* logits  = (const float*)d_in[0];
  const float* logits1 = (const float*)d_in[1];
  const float* pfirst  = (const float*)d_in[2];
  const float* psec    = (const float*)d_in[3];
  float* out = (float*)d_out;
  float* wsf = (float*)d_ws;
  // workspace layout (float offsets):
  float* accum = wsf;                                          // [0..16)
  int* selg = (int*)(wsf + 16);                                // 4*NS ints        @16
  unsigned long long* cand = (unsigned long long*)(wsf + 16 + 4 * NS);  // @8208 (byte%8==0)
  unsigned* aflag = (unsigned*)(wsf + 139280);                 // after cand (131072 floats)
  unsigned* cflag = (unsigned*)(wsf + 139312);
  float* apay = wsf + 139344;                                  // 4*8*1285 = 41120 floats
  float* cpay = wsf + 180464;                                  // 4*8*16 = 512 floats
  float* feaT = wsf + 180976;                                  // 4 branches x [CD][NS] = 8 MB

  static std::once_flag once;
  std::call_once(once, []() {
    (void)hipFuncSetAttribute((const void*)branch_kernel,
                              hipFuncAttributeMaxDynamicSharedMemorySize, DYN_K);
    (void)hipGetLastError();
  });

  // zero accum + selg + cand + flags (fresh cand slots + flag seqs start at 0 -> poll ==n
  // with n>=1 is ABA-free; payload regions need no zeroing, guarded by flags)
  (void)hipMemsetAsync(wsf, 0, (size_t)139344 * 4, stream);
  gp_kernel<<<1024, 256, 0, stream>>>(logits, logits1, accum);
  fps_kernel<<<4 * NB_F, TPB_F, 0, stream>>>(pfirst, psec, selg, cand);
  branch_kernel<<<4 * NB_K, TPB, DYN_K, stream>>>(logits, logits1, pfirst, psec,
                                                  selg, feaT, accum,
                                                  apay, aflag, cpay, cflag);
  fin_kernel<<<1, 1, 0, stream>>>(accum, out);
}